// Round 4
// baseline (222.377 us; speedup 1.0000x reference)
//
#include <hip/hip_runtime.h>

// MSDeformAttn: B=2, LQ=LV=11109, D=256, NH=8, HD=32, NL=3, NP=4
// shapes: (92,92),(46,46),(23,23); starts: 0, 8464, 10580
#define LQn   11109
#define MTOT  22218   // B * LQ

typedef __attribute__((ext_vector_type(8))) short short8;
typedef __attribute__((ext_vector_type(4))) float f32x4;

__device__ __forceinline__ unsigned short f2bf(float f) {
  union { float f; unsigned int u; } v; v.f = f;
  unsigned int r = v.u + 0x7fffu + ((v.u >> 16) & 1u);  // RNE
  return (unsigned short)(r >> 16);
}

__device__ __forceinline__ uint4 pack8(const float4 a, const float4 b) {
  uint4 u;
  u.x = (unsigned)f2bf(a.x) | ((unsigned)f2bf(a.y) << 16);
  u.y = (unsigned)f2bf(a.z) | ((unsigned)f2bf(a.w) << 16);
  u.z = (unsigned)f2bf(b.x) | ((unsigned)f2bf(b.y) << 16);
  u.w = (unsigned)f2bf(b.z) | ((unsigned)f2bf(b.w) << 16);
  return u;
}

// bijective XCD chunk swizzle: consecutive logical blocks -> same XCD
__device__ __forceinline__ int xcd_swz(int bid, int nwg) {
  const int xcd = bid & 7, pos = bid >> 3;
  const int q = nwg >> 3, r = nwg & 7;
  return (xcd < r ? xcd * (q + 1) : r * (q + 1) + (xcd - r) * q) + pos;
}

// ---------------- weight prep: transpose to (N x K) bf16, concat biases ----------------
__global__ __launch_bounds__(256) void prep_weights(
    const float* __restrict__ Wval, const float* __restrict__ Woff,
    const float* __restrict__ Wattn, const float* __restrict__ Wout,
    const float* __restrict__ boff, const float* __restrict__ battn,
    unsigned short* __restrict__ Wval_t, unsigned short* __restrict__ Wcat_t,
    unsigned short* __restrict__ Wout_t, float* __restrict__ bcat) {
  int i = blockIdx.x * 256 + threadIdx.x;   // grid = 288 blocks -> i < 73728
  int n = i >> 8, k = i & 255;              // Wt[n][k] = W[k][n]
  if (n < 256) {
    Wval_t[i] = f2bf(Wval[k * 256 + n]);
    Wout_t[i] = f2bf(Wout[k * 256 + n]);
  }
  float src = (n < 192) ? Woff[k * 192 + n] : Wattn[k * 96 + (n - 192)];
  Wcat_t[i] = f2bf(src);
  if (i < 288) bcat[i] = (i < 192) ? boff[i] : battn[i - 192];
}

// ---------------- fused GEMM1+GEMM2, BM=128 x BN=64, persistent-B LDS ----------------
// 1D grid 174*9 (XCD-chunk swizzled): lb = bm*9 + bnid; bnid<4 -> value proj,
// bnid>=4 -> logits proj. B tile (64 x 256) staged ONCE into LDS; A tile
// double-buffered (fp32 -> bf16 in registers), one barrier per K-step.
__global__ __launch_bounds__(256) void gemm_fused12(
    const float* __restrict__ Aval,           // (M,256) fp32
    const float* __restrict__ Aq,             // (M,256) fp32
    const unsigned short* __restrict__ Bval,  // (256,256) bf16 N-major
    const unsigned short* __restrict__ Bcat,  // (288,256) bf16 N-major
    const float* __restrict__ bval, const float* __restrict__ bcat,
    unsigned short* __restrict__ value16,     // [b][h][pix][32] bf16
    float* __restrict__ logits) {             // (M,288) fp32
  __shared__ unsigned short Bs[64][264];      // 33.8 KB, full-K B tile
  __shared__ unsigned short As[2][128][40];   // 20.5 KB, double-buffered

  const int lb = xcd_swz(blockIdx.x, gridDim.x);
  const int bm = lb / 9;
  const int bnid = lb - bm * 9;
  const bool is2 = bnid >= 4;
  const int bn = is2 ? bnid - 4 : bnid;
  const float* __restrict__ A = is2 ? Aq : Aval;
  const unsigned short* __restrict__ Bt = is2 ? Bcat : Bval;
  const float* __restrict__ bias = is2 ? bcat : bval;
  const int N = is2 ? 288 : 256;

  const int t = threadIdx.x;
  const int wave = t >> 6, lane = t & 63;
  const int wm = wave >> 1, wn = wave & 1;
  const int quad = lane >> 4, l16 = lane & 15;

  const int ar = t >> 2;          // staging row (0..63)
  const int ak = (t & 3) * 8;     // staging k-offset (ushorts)

  // ---- stage B tile once (predicated rows, zero-fill) ----
  {
    const int brg = bn * 64 + ar;
    const bool bv_ok = brg < N;
#pragma unroll
    for (int kk = 0; kk < 8; kk++) {
      uint4 bv = {0u, 0u, 0u, 0u};
      if (bv_ok) bv = *(const uint4*)(Bt + (size_t)brg * 256 + kk * 32 + ak);
      *(uint4*)(&Bs[ar][kk * 32 + ak]) = bv;
    }
  }

  const int rg0 = bm * 128 + ar;
  const int rg1 = rg0 + 64;
  float4 areg[4];
  auto loadA = [&](int kb) {
    areg[0] = (float4){0.f, 0.f, 0.f, 0.f}; areg[1] = areg[0];
    areg[2] = areg[0]; areg[3] = areg[0];
    if (rg0 < MTOT) {
      areg[0] = *(const float4*)(A + (size_t)rg0 * 256 + kb * 32 + ak);
      areg[1] = *(const float4*)(A + (size_t)rg0 * 256 + kb * 32 + ak + 4);
    }
    if (rg1 < MTOT) {
      areg[2] = *(const float4*)(A + (size_t)rg1 * 256 + kb * 32 + ak);
      areg[3] = *(const float4*)(A + (size_t)rg1 * 256 + kb * 32 + ak + 4);
    }
  };
  auto storeA = [&](int buf) {
    *(uint4*)(&As[buf][ar][ak])      = pack8(areg[0], areg[1]);
    *(uint4*)(&As[buf][ar + 64][ak]) = pack8(areg[2], areg[3]);
  };

  loadA(0);
  storeA(0);
  __syncthreads();   // covers B tile + A buf0

  f32x4 acc[4][2];
#pragma unroll
  for (int fi = 0; fi < 4; fi++)
#pragma unroll
    for (int j = 0; j < 2; j++) acc[fi][j] = (f32x4){0.f, 0.f, 0.f, 0.f};

  for (int kb = 0; kb < 8; kb++) {
    const int cur = kb & 1;
    if (kb < 7) loadA(kb + 1);            // issue next loads early
    short8 af[4], bf2[2];
#pragma unroll
    for (int fi = 0; fi < 4; fi++)
      af[fi] = *(const short8*)(&As[cur][wm * 64 + fi * 16 + l16][quad * 8]);
#pragma unroll
    for (int j = 0; j < 2; j++)
      bf2[j] = *(const short8*)(&Bs[wn * 32 + j * 16 + l16][kb * 32 + quad * 8]);
#pragma unroll
    for (int fi = 0; fi < 4; fi++)
#pragma unroll
      for (int j = 0; j < 2; j++)
        acc[fi][j] = __builtin_amdgcn_mfma_f32_16x16x32_bf16(af[fi], bf2[j], acc[fi][j], 0, 0, 0);
    if (kb < 7) storeA(cur ^ 1);          // write next buffer (read next iter)
    __syncthreads();
  }

#pragma unroll
  for (int fi = 0; fi < 4; fi++)
#pragma unroll
    for (int j = 0; j < 2; j++) {
      int colg = bn * 64 + wn * 32 + j * 16 + l16;
      if (colg >= N) continue;
      float bsv = bias[colg];
      int row0 = bm * 128 + wm * 64 + fi * 16 + quad * 4;
#pragma unroll
      for (int r = 0; r < 4; r++) {
        int rg = row0 + r;
        if (rg >= MTOT) continue;
        float v = acc[fi][j][r] + bsv;
        if (is2) {
          logits[(size_t)rg * 288 + colg] = v;
        } else {
          int b = (rg >= LQn) ? 1 : 0;
          int p = rg - b * LQn;
          value16[((size_t)(b * 8 + (colg >> 5)) * LQn + p) * 32 + (colg & 31)] = f2bf(v);
        }
      }
    }
}

// ---------------- GEMM3: A bf16, BM=128 x BN=64, persistent-B LDS ----------------
// 1D grid 174*4 (XCD-chunk swizzled): lb = bm*4 + bn.
__global__ __launch_bounds__(256) void gemm_a16(
    const unsigned short* __restrict__ A,   // (M,256) bf16
    const unsigned short* __restrict__ Bt,  // (256,256) bf16 N-major
    const float* __restrict__ bias,
    float* __restrict__ C) {                // (M,256) fp32
  __shared__ unsigned short Bs[64][264];
  __shared__ unsigned short As[2][128][40];

  const int lb = xcd_swz(blockIdx.x, gridDim.x);
  const int bm = lb >> 2;
  const int bn = lb & 3;

  const int t = threadIdx.x;
  const int wave = t >> 6, lane = t & 63;
  const int wm = wave >> 1, wn = wave & 1;
  const int quad = lane >> 4, l16 = lane & 15;

  const int ar = t >> 2;
  const int ak = (t & 3) * 8;

  // ---- stage B tile once ----
  {
    const int brg = bn * 64 + ar;   // < 256 always
#pragma unroll
    for (int kk = 0; kk < 8; kk++) {
      uint4 bv = *(const uint4*)(Bt + (size_t)brg * 256 + kk * 32 + ak);
      *(uint4*)(&Bs[ar][kk * 32 + ak]) = bv;
    }
  }

  const int rg0 = bm * 128 + ar;
  const int rg1 = rg0 + 64;
  uint4 av0, av1;
  auto loadA = [&](int kb) {
    av0 = (uint4){0u, 0u, 0u, 0u}; av1 = av0;
    if (rg0 < MTOT) av0 = *(const uint4*)(A + (size_t)rg0 * 256 + kb * 32 + ak);
    if (rg1 < MTOT) av1 = *(const uint4*)(A + (size_t)rg1 * 256 + kb * 32 + ak);
  };
  auto storeA = [&](int buf) {
    *(uint4*)(&As[buf][ar][ak])      = av0;
    *(uint4*)(&As[buf][ar + 64][ak]) = av1;
  };

  loadA(0);
  storeA(0);
  __syncthreads();

  f32x4 acc[4][2];
#pragma unroll
  for (int fi = 0; fi < 4; fi++)
#pragma unroll
    for (int j = 0; j < 2; j++) acc[fi][j] = (f32x4){0.f, 0.f, 0.f, 0.f};

  for (int kb = 0; kb < 8; kb++) {
    const int cur = kb & 1;
    if (kb < 7) loadA(kb + 1);
    short8 af[4], bf2[2];
#pragma unroll
    for (int fi = 0; fi < 4; fi++)
      af[fi] = *(const short8*)(&As[cur][wm * 64 + fi * 16 + l16][quad * 8]);
#pragma unroll
    for (int j = 0; j < 2; j++)
      bf2[j] = *(const short8*)(&Bs[wn * 32 + j * 16 + l16][kb * 32 + quad * 8]);
#pragma unroll
    for (int fi = 0; fi < 4; fi++)
#pragma unroll
      for (int j = 0; j < 2; j++)
        acc[fi][j] = __builtin_amdgcn_mfma_f32_16x16x32_bf16(af[fi], bf2[j], acc[fi][j], 0, 0, 0);
    if (kb < 7) storeA(cur ^ 1);
    __syncthreads();
  }

#pragma unroll
  for (int fi = 0; fi < 4; fi++)
#pragma unroll
    for (int j = 0; j < 2; j++) {
      int colg = bn * 64 + wn * 32 + j * 16 + l16;
      float bsv = bias[colg];
      int row0 = bm * 128 + wm * 64 + fi * 16 + quad * 4;
#pragma unroll
      for (int r = 0; r < 4; r++) {
        int rg = row0 + r;
        if (rg < MTOT) C[(size_t)rg * 256 + colg] = acc[fi][j][r] + bsv;
      }
    }
}

// ---------------- sampling + softmax + weighted sum, v6 ----------------
// v5 + software-pipelined phase C: next slot's 4 corner gathers are issued
// while the current slot's FMAs run (8 loads in flight vs compiler's ~2).
__global__ __launch_bounds__(256) void msda_sample4(
    const unsigned short* __restrict__ value16,  // [b][h][pix][32] bf16
    const float* __restrict__ logits,            // (M,288)
    const float* __restrict__ refp,              // (M,3,2) (y,x)
    unsigned short* __restrict__ sampled) {      // (M,256) bf16
  __shared__ float          tw[8][96][4];   // 12.3 KB
  __shared__ unsigned short ti[8][96][4];   // 6.1 KB
  __shared__ float hmx[8][8], hrd[8][8];
  __shared__ float rfs[8][6];

  const int t = threadIdx.x;
  const int nbid = xcd_swz(blockIdx.x, gridDim.x);
  const int qbase = nbid * 8;

  // refp: 48 consecutive floats
  if (t < 48) {
    int q = t / 6;
    if (qbase + q < MTOT) rfs[q][t - q * 6] = refp[(size_t)qbase * 6 + t];
  }
  // softmax stats: 64 (q,h) tasks, logits read from global (L2-hot)
  if (t >= 64 && t < 128) {
    int tt = t - 64;
    int q = tt >> 3, h = tt & 7;
    int bq = qbase + q;
    if (bq < MTOT) {
      const float* lrow = logits + (size_t)bq * 288 + 192 + h * 12;
      float mx = -1e30f;
#pragma unroll
      for (int i = 0; i < 12; i++) mx = fmaxf(mx, lrow[i]);
      float den = 0.f;
#pragma unroll
      for (int i = 0; i < 12; i++) den += __expf(lrow[i] - mx);
      hmx[q][h] = mx;
      hrd[q][h] = 1.0f / den;
    }
  }
  __syncthreads();

  // build tables: 8q x 96 slots = 768 tasks
  {
    const int Hs[3] = {92, 46, 23};
    const int Ss[3] = {0, 8464, 10580};
#pragma unroll
    for (int r = 0; r < 3; r++) {
      const int task = t + r * 256;
      const int q = task / 96, s = task - q * 96;
      const int bq = qbase + q;
      if (bq < MTOT) {
        const int h = s / 12, pl = s - h * 12;
        const int l = pl >> 2;
        const int H = Hs[l], W = Hs[l], S = Ss[l];
        const float* lrow = logits + (size_t)bq * 288;
        const float aw = __expf(lrow[192 + s] - hmx[q][h]) * hrd[q][h];
        const float offy = lrow[2 * s], offx = lrow[2 * s + 1];
        const float x = rfs[q][l * 2 + 1] * W + offx - 0.5f;
        const float y = rfs[q][l * 2 + 0] * H + offy - 0.5f;
        const float xf = floorf(x), yf = floorf(y);
        const int x0 = (int)xf, y0 = (int)yf;
        const float lx = x - xf, ly = y - yf;
        const bool xv0 = (x0 >= 0) & (x0 < W), xv1 = (x0 + 1 >= 0) & (x0 + 1 < W);
        const bool yv0 = (y0 >= 0) & (y0 < H), yv1 = (y0 + 1 >= 0) & (y0 + 1 < H);
        const int xc0 = min(max(x0, 0), W - 1), xc1 = min(max(x0 + 1, 0), W - 1);
        const int yc0 = min(max(y0, 0), H - 1), yc1 = min(max(y0 + 1, 0), H - 1);
        const int slot = pl * 8 + h;
        ti[q][slot][0] = (unsigned short)(S + yc0 * W + xc0);
        ti[q][slot][1] = (unsigned short)(S + yc0 * W + xc1);
        ti[q][slot][2] = (unsigned short)(S + yc1 * W + xc0);
        ti[q][slot][3] = (unsigned short)(S + yc1 * W + xc1);
        tw[q][slot][0] = (yv0 & xv0) ? aw * (1.f - ly) * (1.f - lx) : 0.f;
        tw[q][slot][1] = (yv0 & xv1) ? aw * (1.f - ly) * lx : 0.f;
        tw[q][slot][2] = (yv1 & xv0) ? aw * ly * (1.f - lx) : 0.f;
        tw[q][slot][3] = (yv1 & xv1) ? aw * ly * lx : 0.f;
      }
    }
  }
  __syncthreads();

  // gather + weighted sum: wave w handles queries qbase + 2w + {0,1}
  {
    const int w = t >> 6, lane = t & 63;
    const int q = w * 2 + (lane >> 5);
    const int h = (lane >> 2) & 7, cg = lane & 3;
    const int bq = qbase + q;
    const bool qv = bq < MTOT;
    const int bqc = qv ? bq : 0;
    const char* __restrict__ vb =
        (const char*)value16 + (size_t)(bqc / LQn) * ((size_t)LQn * 512);
    const unsigned laneoff = (unsigned)h * (LQn * 64u) + (unsigned)cg * 16u;

    float a0 = 0.f, a1 = 0.f, a2 = 0.f, a3 = 0.f;
    float a4 = 0.f, a5 = 0.f, a6 = 0.f, a7 = 0.f;

#define ACC8(u, wgt)                                  \
    a0 += (wgt) * __uint_as_float((u).x << 16);       \
    a1 += (wgt) * __uint_as_float((u).x & 0xffff0000u); \
    a2 += (wgt) * __uint_as_float((u).y << 16);       \
    a3 += (wgt) * __uint_as_float((u).y & 0xffff0000u); \
    a4 += (wgt) * __uint_as_float((u).z << 16);       \
    a5 += (wgt) * __uint_as_float((u).z & 0xffff0000u); \
    a6 += (wgt) * __uint_as_float((u).w << 16);       \
    a7 += (wgt) * __uint_as_float((u).w & 0xffff0000u);

    // software pipeline: slot p's gathers in flight while slot p-1 FMAs run
    ushort4 tc = *(const ushort4*)(&ti[q][h][0]);       // slot 0*8+h
    f32x4   wc = *(const f32x4*)(&tw[q][h][0]);
    uint4 u0 = *(const uint4*)(vb + (((unsigned)tc.x << 6) + laneoff));
    uint4 u1 = *(const uint4*)(vb + (((unsigned)tc.y << 6) + laneoff));
    uint4 u2 = *(const uint4*)(vb + (((unsigned)tc.z << 6) + laneoff));
    uint4 u3 = *(const uint4*)(vb + (((unsigned)tc.w << 6) + laneoff));
#pragma unroll
    for (int p = 0; p < 12; p++) {
      uint4 n0, n1, n2, n3;
      f32x4 wn2;
      if (p < 11) {
        const int slot = (p + 1) * 8 + h;
        const ushort4 tn = *(const ushort4*)(&ti[q][slot][0]);
        wn2 = *(const f32x4*)(&tw[q][slot][0]);
        n0 = *(const uint4*)(vb + (((unsigned)tn.x << 6) + laneoff));
        n1 = *(const uint4*)(vb + (((unsigned)tn.y << 6) + laneoff));
        n2 = *(const uint4*)(vb + (((unsigned)tn.z << 6) + laneoff));
        n3 = *(const uint4*)(vb + (((unsigned)tn.w << 6) + laneoff));
      }
      ACC8(u0, wc[0]);
      ACC8(u1, wc[1]);
      ACC8(u2, wc[2]);
      ACC8(u3, wc[3]);
      if (p < 11) { u0 = n0; u1 = n1; u2 = n2; u3 = n3; wc = wn2; }
    }
#undef ACC8

    if (qv) {
      uint4 o;
      o.x = (unsigned)f2bf(a0) | ((unsigned)f2bf(a1) << 16);
      o.y = (unsigned)f2bf(a2) | ((unsigned)f2bf(a3) << 16);
      o.z = (unsigned)f2bf(a4) | ((unsigned)f2bf(a5) << 16);
      o.w = (unsigned)f2bf(a6) | ((unsigned)f2bf(a7) << 16);
      *(uint4*)(sampled + (size_t)bq * 256 + h * 32 + cg * 8) = o;
    }
  }
}

// ---------------- host launch ----------------
extern "C" void kernel_launch(void* const* d_in, const int* in_sizes, int n_in,
                              void* d_out, int out_size, void* d_ws, size_t ws_size,
                              hipStream_t stream) {
  const float* query      = (const float*)d_in[0];
  const float* refp       = (const float*)d_in[1];
  const float* value_flat = (const float*)d_in[2];
  const float* W_val      = (const float*)d_in[3];
  const float* b_val      = (const float*)d_in[4];
  const float* W_off      = (const float*)d_in[5];
  const float* b_off      = (const float*)d_in[6];
  const float* W_attn     = (const float*)d_in[7];
  const float* b_attn     = (const float*)d_in[8];
  const float* W_out      = (const float*)d_in[9];
  const float* b_out      = (const float*)d_in[10];

  char* w = (char*)d_ws;
  size_t o = 0;
  auto carve = [&](size_t bytes) -> void* {
    void* p = (void*)(w + o);
    o += (bytes + 255) & ~(size_t)255;
    return p;
  };
  unsigned short* Wval_t  = (unsigned short*)carve(256 * 256 * 2);
  unsigned short* Wcat_t  = (unsigned short*)carve(288 * 256 * 2);
  unsigned short* Wout_t  = (unsigned short*)carve(256 * 256 * 2);
  float*          bcat    = (float*)carve(288 * 4);
  unsigned short* value16 = (unsigned short*)carve((size_t)MTOT * 256 * 2);
  float*          logits  = (float*)carve((size_t)MTOT * 288 * 4);
  unsigned short* samp_bf = (unsigned short*)carve((size_t)MTOT * 256 * 2);

  prep_weights<<<288, 256, 0, stream>>>(W_val, W_off, W_attn, W_out, b_off, b_attn,
                                        Wval_t, Wcat_t, Wout_t, bcat);

  const int mg = (MTOT + 127) / 128;             // 174
  gemm_fused12<<<mg * 9, 256, 0, stream>>>(value_flat, query, Wval_t, Wcat_t,
                                           b_val, bcat, value16, logits);

  const int sgrid = (MTOT + 7) / 8;              // 2778
  msda_sample4<<<sgrid, 256, 0, stream>>>(value16, logits, refp, samp_bf);

  gemm_a16<<<mg * 4, 256, 0, stream>>>(samp_bf, Wout_t, b_out, (float*)d_out);
}

// Round 5
// 214.660 us; speedup vs baseline: 1.0360x; 1.0360x over previous
//
#include <hip/hip_runtime.h>

// MSDeformAttn: B=2, LQ=LV=11109, D=256, NH=8, HD=32, NL=3, NP=4
// shapes: (92,92),(46,46),(23,23); starts: 0, 8464, 10580
#define LQn   11109
#define MTOT  22218   // B * LQ

typedef __attribute__((ext_vector_type(8))) short short8;
typedef __attribute__((ext_vector_type(4))) float f32x4;

__device__ __forceinline__ unsigned short f2bf(float f) {
  union { float f; unsigned int u; } v; v.f = f;
  unsigned int r = v.u + 0x7fffu + ((v.u >> 16) & 1u);  // RNE
  return (unsigned short)(r >> 16);
}

__device__ __forceinline__ uint4 pack8(const float4 a, const float4 b) {
  uint4 u;
  u.x = (unsigned)f2bf(a.x) | ((unsigned)f2bf(a.y) << 16);
  u.y = (unsigned)f2bf(a.z) | ((unsigned)f2bf(a.w) << 16);
  u.z = (unsigned)f2bf(b.x) | ((unsigned)f2bf(b.y) << 16);
  u.w = (unsigned)f2bf(b.z) | ((unsigned)f2bf(b.w) << 16);
  return u;
}

// bijective XCD chunk swizzle: consecutive logical blocks -> same XCD
__device__ __forceinline__ int xcd_swz(int bid, int nwg) {
  const int xcd = bid & 7, pos = bid >> 3;
  const int q = nwg >> 3, r = nwg & 7;
  return (xcd < r ? xcd * (q + 1) : r * (q + 1) + (xcd - r) * q) + pos;
}

// ---------------- weight prep: transpose to (N x K) bf16, concat biases ----------------
__global__ __launch_bounds__(256) void prep_weights(
    const float* __restrict__ Wval, const float* __restrict__ Woff,
    const float* __restrict__ Wattn, const float* __restrict__ Wout,
    const float* __restrict__ boff, const float* __restrict__ battn,
    unsigned short* __restrict__ Wval_t, unsigned short* __restrict__ Wcat_t,
    unsigned short* __restrict__ Wout_t, float* __restrict__ bcat) {
  int i = blockIdx.x * 256 + threadIdx.x;   // grid = 288 blocks -> i < 73728
  int n = i >> 8, k = i & 255;              // Wt[n][k] = W[k][n]
  if (n < 256) {
    Wval_t[i] = f2bf(Wval[k * 256 + n]);
    Wout_t[i] = f2bf(Wout[k * 256 + n]);
  }
  float src = (n < 192) ? Woff[k * 192 + n] : Wattn[k * 96 + (n - 192)];
  Wcat_t[i] = f2bf(src);
  if (i < 288) bcat[i] = (i < 192) ? boff[i] : battn[i - 192];
}

// ---------------- fused GEMM1+GEMM2: A-panel LDS once, ONE barrier, B direct from L2 ----
// grid (348, 2): y=0 -> value proj (A=value_flat, B=Bval, N=256, bf16 head-major out)
//                y=1 -> logits proj (A=query, B=Bcat, N=288, fp32 out)
// B fragments (16B, N-major) are loaded straight from global (B is 128-144 KB,
// L2-resident on every XCD) -> zero staging barriers in the main loop.
__global__ __launch_bounds__(256) void gemm_fused12(
    const float* __restrict__ Aval,           // (M,256) fp32
    const float* __restrict__ Aq,             // (M,256) fp32
    const unsigned short* __restrict__ Bval,  // (256,256) bf16 N-major
    const unsigned short* __restrict__ Bcat,  // (288,256) bf16 N-major
    const float* __restrict__ bval, const float* __restrict__ bcat,
    unsigned short* __restrict__ value16,     // [b][h][pix][32] bf16
    float* __restrict__ logits) {             // (M,288) fp32
  __shared__ unsigned short As[64][264];      // 33.8 KB (pad 8 -> 2-way banks)

  const bool is2 = blockIdx.y == 1;
  const float* __restrict__ A = is2 ? Aq : Aval;
  const unsigned short* __restrict__ Bt = is2 ? Bcat : Bval;
  const float* __restrict__ bias = is2 ? bcat : bval;
  const int N = is2 ? 288 : 256;
  const int NB = is2 ? 5 : 4;

  const int bm = blockIdx.x;
  const int t = threadIdx.x;
  const int wave = t >> 6, lane = t & 63;
  const int wm = wave >> 1, wn = wave & 1;
  const int quad = lane >> 4, l16 = lane & 15;

  const int ldr = t >> 2;
  const int ldk = (t & 3) * 8;
  const int arow = bm * 64 + ldr;

  // ---- stage A panel once (fp32 -> bf16), coalesced ----
#pragma unroll
  for (int kb = 0; kb < 8; kb++) {
    float4 a0 = {0.f, 0.f, 0.f, 0.f}, a1 = a0;
    if (arow < MTOT) {
      a0 = *(const float4*)(A + (size_t)arow * 256 + kb * 32 + ldk);
      a1 = *(const float4*)(A + (size_t)arow * 256 + kb * 32 + ldk + 4);
    }
    *(uint4*)(&As[ldr][kb * 32 + ldk]) = pack8(a0, a1);
  }
  __syncthreads();   // the ONLY barrier

  const int brow0 = wn * 32 + l16;   // +bn*64; j=0 row, j=1 adds 16

  for (int bn = 0; bn < NB; bn++) {
    f32x4 acc[2][2];
#pragma unroll
    for (int i = 0; i < 2; i++)
#pragma unroll
      for (int j = 0; j < 2; j++) acc[i][j] = (f32x4){0.f, 0.f, 0.f, 0.f};

    const int br0 = bn * 64 + brow0;
    const int br1 = br0 + 16;
    const unsigned short* bp0 = Bt + (size_t)br0 * 256 + quad * 8;
    const unsigned short* bp1 = Bt + (size_t)br1 * 256 + quad * 8;
    const bool v0 = br0 < N, v1 = br1 < N;

#pragma unroll
    for (int kb = 0; kb < 8; kb++) {
      short8 af[2], bfr[2];
      af[0] = *(const short8*)(&As[wm * 32 + l16][kb * 32 + quad * 8]);
      af[1] = *(const short8*)(&As[wm * 32 + 16 + l16][kb * 32 + quad * 8]);
      bfr[0] = v0 ? *(const short8*)(bp0 + kb * 32) : (short8){0,0,0,0,0,0,0,0};
      bfr[1] = v1 ? *(const short8*)(bp1 + kb * 32) : (short8){0,0,0,0,0,0,0,0};
#pragma unroll
      for (int i = 0; i < 2; i++)
#pragma unroll
        for (int j = 0; j < 2; j++)
          acc[i][j] = __builtin_amdgcn_mfma_f32_16x16x32_bf16(af[i], bfr[j], acc[i][j], 0, 0, 0);
    }

#pragma unroll
    for (int i = 0; i < 2; i++)
#pragma unroll
      for (int j = 0; j < 2; j++) {
        int colg = bn * 64 + wn * 32 + j * 16 + l16;
        if (colg >= N) continue;
        float bsv = bias[colg];
        int row0 = bm * 64 + wm * 32 + i * 16 + quad * 4;
#pragma unroll
        for (int r = 0; r < 4; r++) {
          int rg = row0 + r;
          if (rg >= MTOT) continue;
          float v = acc[i][j][r] + bsv;
          if (is2) {
            logits[(size_t)rg * 288 + colg] = v;
          } else {
            int b = (rg >= LQn) ? 1 : 0;
            int p = rg - b * LQn;
            value16[((size_t)(b * 8 + (colg >> 5)) * LQn + p) * 32 + (colg & 31)] = f2bf(v);
          }
        }
      }
  }
}

// ---------------- GEMM3: same skeleton, A bf16, out fp32 (out proj) ----------------
__global__ __launch_bounds__(256) void gemm_a16(
    const unsigned short* __restrict__ A,   // (M,256) bf16
    const unsigned short* __restrict__ Bt,  // (256,256) bf16 N-major
    const float* __restrict__ bias,
    float* __restrict__ C) {                // (M,256) fp32
  __shared__ unsigned short As[64][264];

  const int bm = blockIdx.x;
  const int t = threadIdx.x;
  const int wave = t >> 6, lane = t & 63;
  const int wm = wave >> 1, wn = wave & 1;
  const int quad = lane >> 4, l16 = lane & 15;

  const int ldr = t >> 2;
  const int ldk = (t & 3) * 8;
  const int arow = bm * 64 + ldr;

#pragma unroll
  for (int kb = 0; kb < 8; kb++) {
    uint4 av = {0u, 0u, 0u, 0u};
    if (arow < MTOT) av = *(const uint4*)(A + (size_t)arow * 256 + kb * 32 + ldk);
    *(uint4*)(&As[ldr][kb * 32 + ldk]) = av;
  }
  __syncthreads();   // the ONLY barrier

  const int brow0 = wn * 32 + l16;

  for (int bn = 0; bn < 4; bn++) {
    f32x4 acc[2][2];
#pragma unroll
    for (int i = 0; i < 2; i++)
#pragma unroll
      for (int j = 0; j < 2; j++) acc[i][j] = (f32x4){0.f, 0.f, 0.f, 0.f};

    const int br0 = bn * 64 + brow0;         // < 256 always
    const unsigned short* bp0 = Bt + (size_t)br0 * 256 + quad * 8;
    const unsigned short* bp1 = bp0 + 16 * 256;

#pragma unroll
    for (int kb = 0; kb < 8; kb++) {
      short8 af[2], bfr[2];
      af[0] = *(const short8*)(&As[wm * 32 + l16][kb * 32 + quad * 8]);
      af[1] = *(const short8*)(&As[wm * 32 + 16 + l16][kb * 32 + quad * 8]);
      bfr[0] = *(const short8*)(bp0 + kb * 32);
      bfr[1] = *(const short8*)(bp1 + kb * 32);
#pragma unroll
      for (int i = 0; i < 2; i++)
#pragma unroll
        for (int j = 0; j < 2; j++)
          acc[i][j] = __builtin_amdgcn_mfma_f32_16x16x32_bf16(af[i], bfr[j], acc[i][j], 0, 0, 0);
    }

#pragma unroll
    for (int i = 0; i < 2; i++)
#pragma unroll
      for (int j = 0; j < 2; j++) {
        int colg = bn * 64 + wn * 32 + j * 16 + l16;
        float bsv = bias[colg];
        int row0 = bm * 64 + wm * 32 + i * 16 + quad * 4;
#pragma unroll
        for (int r = 0; r < 4; r++) {
          int rg = row0 + r;
          if (rg < MTOT) C[(size_t)rg * 256 + colg] = acc[i][j][r] + bsv;
        }
      }
  }
}

// ---------------- sampling + softmax + weighted sum, v6 ----------------
// XCD-chunk swizzle + software-pipelined phase C (next slot's 4 corner
// gathers in flight while current slot's FMAs run).
__global__ __launch_bounds__(256) void msda_sample4(
    const unsigned short* __restrict__ value16,  // [b][h][pix][32] bf16
    const float* __restrict__ logits,            // (M,288)
    const float* __restrict__ refp,              // (M,3,2) (y,x)
    unsigned short* __restrict__ sampled) {      // (M,256) bf16
  __shared__ float          tw[8][96][4];   // 12.3 KB
  __shared__ unsigned short ti[8][96][4];   // 6.1 KB
  __shared__ float hmx[8][8], hrd[8][8];
  __shared__ float rfs[8][6];

  const int t = threadIdx.x;
  const int nbid = xcd_swz(blockIdx.x, gridDim.x);
  const int qbase = nbid * 8;

  // refp: 48 consecutive floats
  if (t < 48) {
    int q = t / 6;
    if (qbase + q < MTOT) rfs[q][t - q * 6] = refp[(size_t)qbase * 6 + t];
  }
  // softmax stats: 64 (q,h) tasks, logits read from global (L2-hot)
  if (t >= 64 && t < 128) {
    int tt = t - 64;
    int q = tt >> 3, h = tt & 7;
    int bq = qbase + q;
    if (bq < MTOT) {
      const float* lrow = logits + (size_t)bq * 288 + 192 + h * 12;
      float mx = -1e30f;
#pragma unroll
      for (int i = 0; i < 12; i++) mx = fmaxf(mx, lrow[i]);
      float den = 0.f;
#pragma unroll
      for (int i = 0; i < 12; i++) den += __expf(lrow[i] - mx);
      hmx[q][h] = mx;
      hrd[q][h] = 1.0f / den;
    }
  }
  __syncthreads();

  // build tables: 8q x 96 slots = 768 tasks
  {
    const int Hs[3] = {92, 46, 23};
    const int Ss[3] = {0, 8464, 10580};
#pragma unroll
    for (int r = 0; r < 3; r++) {
      const int task = t + r * 256;
      const int q = task / 96, s = task - q * 96;
      const int bq = qbase + q;
      if (bq < MTOT) {
        const int h = s / 12, pl = s - h * 12;
        const int l = pl >> 2;
        const int H = Hs[l], W = Hs[l], S = Ss[l];
        const float* lrow = logits + (size_t)bq * 288;
        const float aw = __expf(lrow[192 + s] - hmx[q][h]) * hrd[q][h];
        const float offy = lrow[2 * s], offx = lrow[2 * s + 1];
        const float x = rfs[q][l * 2 + 1] * W + offx - 0.5f;
        const float y = rfs[q][l * 2 + 0] * H + offy - 0.5f;
        const float xf = floorf(x), yf = floorf(y);
        const int x0 = (int)xf, y0 = (int)yf;
        const float lx = x - xf, ly = y - yf;
        const bool xv0 = (x0 >= 0) & (x0 < W), xv1 = (x0 + 1 >= 0) & (x0 + 1 < W);
        const bool yv0 = (y0 >= 0) & (y0 < H), yv1 = (y0 + 1 >= 0) & (y0 + 1 < H);
        const int xc0 = min(max(x0, 0), W - 1), xc1 = min(max(x0 + 1, 0), W - 1);
        const int yc0 = min(max(y0, 0), H - 1), yc1 = min(max(y0 + 1, 0), H - 1);
        const int slot = pl * 8 + h;
        ti[q][slot][0] = (unsigned short)(S + yc0 * W + xc0);
        ti[q][slot][1] = (unsigned short)(S + yc0 * W + xc1);
        ti[q][slot][2] = (unsigned short)(S + yc1 * W + xc0);
        ti[q][slot][3] = (unsigned short)(S + yc1 * W + xc1);
        tw[q][slot][0] = (yv0 & xv0) ? aw * (1.f - ly) * (1.f - lx) : 0.f;
        tw[q][slot][1] = (yv0 & xv1) ? aw * (1.f - ly) * lx : 0.f;
        tw[q][slot][2] = (yv1 & xv0) ? aw * ly * (1.f - lx) : 0.f;
        tw[q][slot][3] = (yv1 & xv1) ? aw * ly * lx : 0.f;
      }
    }
  }
  __syncthreads();

  // gather + weighted sum: wave w handles queries qbase + 2w + {0,1}
  {
    const int w = t >> 6, lane = t & 63;
    const int q = w * 2 + (lane >> 5);
    const int h = (lane >> 2) & 7, cg = lane & 3;
    const int bq = qbase + q;
    const bool qv = bq < MTOT;
    const int bqc = qv ? bq : 0;
    const char* __restrict__ vb =
        (const char*)value16 + (size_t)(bqc / LQn) * ((size_t)LQn * 512);
    const unsigned laneoff = (unsigned)h * (LQn * 64u) + (unsigned)cg * 16u;

    float a0 = 0.f, a1 = 0.f, a2 = 0.f, a3 = 0.f;
    float a4 = 0.f, a5 = 0.f, a6 = 0.f, a7 = 0.f;

#define ACC8(u, wgt)                                  \
    a0 += (wgt) * __uint_as_float((u).x << 16);       \
    a1 += (wgt) * __uint_as_float((u).x & 0xffff0000u); \
    a2 += (wgt) * __uint_as_float((u).y << 16);       \
    a3 += (wgt) * __uint_as_float((u).y & 0xffff0000u); \
    a4 += (wgt) * __uint_as_float((u).z << 16);       \
    a5 += (wgt) * __uint_as_float((u).z & 0xffff0000u); \
    a6 += (wgt) * __uint_as_float((u).w << 16);       \
    a7 += (wgt) * __uint_as_float((u).w & 0xffff0000u);

    // software pipeline: slot p's gathers in flight while slot p-1 FMAs run
    ushort4 tc = *(const ushort4*)(&ti[q][h][0]);       // slot 0*8+h
    f32x4   wc = *(const f32x4*)(&tw[q][h][0]);
    uint4 u0 = *(const uint4*)(vb + (((unsigned)tc.x << 6) + laneoff));
    uint4 u1 = *(const uint4*)(vb + (((unsigned)tc.y << 6) + laneoff));
    uint4 u2 = *(const uint4*)(vb + (((unsigned)tc.z << 6) + laneoff));
    uint4 u3 = *(const uint4*)(vb + (((unsigned)tc.w << 6) + laneoff));
#pragma unroll
    for (int p = 0; p < 12; p++) {
      uint4 n0, n1, n2, n3;
      f32x4 wn2;
      if (p < 11) {
        const int slot = (p + 1) * 8 + h;
        const ushort4 tn = *(const ushort4*)(&ti[q][slot][0]);
        wn2 = *(const f32x4*)(&tw[q][slot][0]);
        n0 = *(const uint4*)(vb + (((unsigned)tn.x << 6) + laneoff));
        n1 = *(const uint4*)(vb + (((unsigned)tn.y << 6) + laneoff));
        n2 = *(const uint4*)(vb + (((unsigned)tn.z << 6) + laneoff));
        n3 = *(const uint4*)(vb + (((unsigned)tn.w << 6) + laneoff));
      }
      ACC8(u0, wc[0]);
      ACC8(u1, wc[1]);
      ACC8(u2, wc[2]);
      ACC8(u3, wc[3]);
      if (p < 11) { u0 = n0; u1 = n1; u2 = n2; u3 = n3; wc = wn2; }
    }
#undef ACC8

    if (qv) {
      uint4 o;
      o.x = (unsigned)f2bf(a0) | ((unsigned)f2bf(a1) << 16);
      o.y = (unsigned)f2bf(a2) | ((unsigned)f2bf(a3) << 16);
      o.z = (unsigned)f2bf(a4) | ((unsigned)f2bf(a5) << 16);
      o.w = (unsigned)f2bf(a6) | ((unsigned)f2bf(a7) << 16);
      *(uint4*)(sampled + (size_t)bq * 256 + h * 32 + cg * 8) = o;
    }
  }
}

// ---------------- host launch ----------------
extern "C" void kernel_launch(void* const* d_in, const int* in_sizes, int n_in,
                              void* d_out, int out_size, void* d_ws, size_t ws_size,
                              hipStream_t stream) {
  const float* query      = (const float*)d_in[0];
  const float* refp       = (const float*)d_in[1];
  const float* value_flat = (const float*)d_in[2];
  const float* W_val      = (const float*)d_in[3];
  const float* b_val      = (const float*)d_in[4];
  const float* W_off      = (const float*)d_in[5];
  const float* b_off      = (const float*)d_in[6];
  const float* W_attn     = (const float*)d_in[7];
  const float* b_attn     = (const float*)d_in[8];
  const float* W_out      = (const float*)d_in[9];
  const float* b_out      = (const float*)d_in[10];

  char* w = (char*)d_ws;
  size_t o = 0;
  auto carve = [&](size_t bytes) -> void* {
    void* p = (void*)(w + o);
    o += (bytes + 255) & ~(size_t)255;
    return p;
  };
  unsigned short* Wval_t  = (unsigned short*)carve(256 * 256 * 2);
  unsigned short* Wcat_t  = (unsigned short*)carve(288 * 256 * 2);
  unsigned short* Wout_t  = (unsigned short*)carve(256 * 256 * 2);
  float*          bcat    = (float*)carve(288 * 4);
  unsigned short* value16 = (unsigned short*)carve((size_t)MTOT * 256 * 2);
  float*          logits  = (float*)carve((size_t)MTOT * 288 * 4);
  unsigned short* samp_bf = (unsigned short*)carve((size_t)MTOT * 256 * 2);

  prep_weights<<<288, 256, 0, stream>>>(W_val, W_off, W_attn, W_out, b_off, b_attn,
                                        Wval_t, Wcat_t, Wout_t, bcat);

  const int mg = (MTOT + 63) / 64;               // 348
  dim3 g12(mg, 2);                               // y=0 value proj, y=1 logits proj
  gemm_fused12<<<g12, 256, 0, stream>>>(value_flat, query, Wval_t, Wcat_t,
                                        b_val, bcat, value16, logits);

  const int sgrid = (MTOT + 7) / 8;              // 2778
  msda_sample4<<<sgrid, 256, 0, stream>>>(value16, logits, refp, samp_bf);

  gemm_a16<<<mg, 256, 0, stream>>>(samp_bf, Wout_t, b_out, (float*)d_out);
}